// Round 2
// baseline (4555.761 us; speedup 1.0000x reference)
//
#include <hip/hip_runtime.h>
#include <cstdint>
#include <cstddef>

#define B_TOTAL 65536
#define SDIM 64
#define ADIM 32
#define LDIM 64
#define HDIM 1024
#define NEMB 1024

// ---------------------------------------------------------------------------
// Generic fp32 GEMM: C[M,N] = act(A[M,K] @ W[K,N] + bias)
// BM=128, BK=16, 256 threads (4 waves), per-thread 8 x TN register tile.
// A is staged transposed in LDS (At[k][row]); W staged as Bt[k][n]; +4 pad
// keeps float4 LDS reads at <=2-way bank conflicts (free per m136).
// ACT: 0 = relu, 1 = tanh, 2 = none.  CONCAT: A = [A0 | A1] row-wise.
// LDS ~17 KB (well under the 64 KB per-workgroup static limit).
// ---------------------------------------------------------------------------
template <int BN, int ACT, bool CONCAT>
__global__ __launch_bounds__(256) void gemm_f32(
    const float* __restrict__ A0, const float* __restrict__ A1, int a0w,
    int K, const float* __restrict__ W, const float* __restrict__ bias,
    float* __restrict__ Co, int N)
{
    constexpr int TN = BN / 16;          // 8 / 4 / 2
    __shared__ float At[16][132];
    __shared__ float Bt[16][BN + 4];

    const int tid = threadIdx.x;
    const int m0 = blockIdx.x * 128;
    const int n0 = blockIdx.y * BN;
    const int r = tid >> 4;              // 0..15 row group
    const int c = tid & 15;              // 0..15 col group

    const int a1w = K - a0w;

    float acc[8][TN];
#pragma unroll
    for (int i = 0; i < 8; ++i)
#pragma unroll
        for (int j = 0; j < TN; ++j) acc[i][j] = 0.f;

    for (int k0 = 0; k0 < K; k0 += 16) {
        // ---- stage A tile (128 rows x 16 cols, transposed) ----
#pragma unroll
        for (int it = 0; it < 2; ++it) {
            int idx = tid + it * 256;     // 0..511
            int row = idx >> 2;           // 0..127
            int lf = idx & 3;             // float4 slot in the 16 cols
            int col = k0 + lf * 4;
            const float* src;
            if (CONCAT) {
                if (col < a0w) src = A0 + (size_t)(m0 + row) * a0w + col;
                else           src = A1 + (size_t)(m0 + row) * a1w + (col - a0w);
            } else {
                src = A0 + (size_t)(m0 + row) * K + col;
            }
            float4 v = *(const float4*)src;
            At[lf * 4 + 0][row] = v.x;
            At[lf * 4 + 1][row] = v.y;
            At[lf * 4 + 2][row] = v.z;
            At[lf * 4 + 3][row] = v.w;
        }
        // ---- stage B tile (16 rows x BN cols) ----
        constexpr int NF4 = BN / 4;
        constexpr int NEL = 16 * NF4;
        if constexpr (NEL >= 256) {
#pragma unroll
            for (int it = 0; it < NEL / 256; ++it) {
                int idx = tid + it * 256;
                int kk = idx / NF4;
                int f = idx % NF4;
                float4 v = *(const float4*)(W + (size_t)(k0 + kk) * N + n0 + f * 4);
                *(float4*)&Bt[kk][f * 4] = v;
            }
        } else {
            if (tid < NEL) {
                int kk = tid / NF4;
                int f = tid % NF4;
                float4 v = *(const float4*)(W + (size_t)(k0 + kk) * N + n0 + f * 4);
                *(float4*)&Bt[kk][f * 4] = v;
            }
        }
        __syncthreads();

        // ---- compute ----
#pragma unroll
        for (int kk = 0; kk < 16; ++kk) {
            float a[8];
            float4 av0 = *(const float4*)&At[kk][r * 8];
            float4 av1 = *(const float4*)&At[kk][r * 8 + 4];
            a[0] = av0.x; a[1] = av0.y; a[2] = av0.z; a[3] = av0.w;
            a[4] = av1.x; a[5] = av1.y; a[6] = av1.z; a[7] = av1.w;
            float b[TN];
            if constexpr (BN == 128) {
                float4 b0 = *(const float4*)&Bt[kk][c * 4];
                float4 b1 = *(const float4*)&Bt[kk][64 + c * 4];
                b[0] = b0.x; b[1] = b0.y; b[2] = b0.z; b[3] = b0.w;
                b[4] = b1.x; b[5] = b1.y; b[6] = b1.z; b[7] = b1.w;
            } else if constexpr (BN == 64) {
                float4 b0 = *(const float4*)&Bt[kk][c * 4];
                b[0] = b0.x; b[1] = b0.y; b[2] = b0.z; b[3] = b0.w;
            } else {
                float2 b0 = *(const float2*)&Bt[kk][c * 2];
                b[0] = b0.x; b[1] = b0.y;
            }
#pragma unroll
            for (int i = 0; i < 8; ++i)
#pragma unroll
                for (int j = 0; j < TN; ++j)
                    acc[i][j] = fmaf(a[i], b[j], acc[i][j]);
        }
        __syncthreads();
    }

    // ---- epilogue: bias + activation, vectorized stores ----
#pragma unroll
    for (int i = 0; i < 8; ++i) {
        size_t row = (size_t)(m0 + r * 8 + i);
        if constexpr (BN == 128) {
            float4 v0, v1;
            float e[8];
#pragma unroll
            for (int j = 0; j < 8; ++j) {
                int col = (j < 4) ? (c * 4 + j) : (64 + c * 4 + (j - 4));
                float v = acc[i][j] + bias[n0 + col];
                if (ACT == 0) v = fmaxf(v, 0.f);
                else if (ACT == 1) v = tanhf(v);
                e[j] = v;
            }
            v0.x = e[0]; v0.y = e[1]; v0.z = e[2]; v0.w = e[3];
            v1.x = e[4]; v1.y = e[5]; v1.z = e[6]; v1.w = e[7];
            *(float4*)&Co[row * N + n0 + c * 4] = v0;
            *(float4*)&Co[row * N + n0 + 64 + c * 4] = v1;
        } else if constexpr (BN == 64) {
            float4 v0;
            float e[4];
#pragma unroll
            for (int j = 0; j < 4; ++j) {
                float v = acc[i][j] + bias[n0 + c * 4 + j];
                if (ACT == 0) v = fmaxf(v, 0.f);
                else if (ACT == 1) v = tanhf(v);
                e[j] = v;
            }
            v0.x = e[0]; v0.y = e[1]; v0.z = e[2]; v0.w = e[3];
            *(float4*)&Co[row * N + n0 + c * 4] = v0;
        } else {
            float2 v0;
            float e[2];
#pragma unroll
            for (int j = 0; j < 2; ++j) {
                float v = acc[i][j] + bias[n0 + c * 2 + j];
                if (ACT == 0) v = fmaxf(v, 0.f);
                else if (ACT == 1) v = tanhf(v);
                e[j] = v;
            }
            v0.x = e[0]; v0.y = e[1];
            *(float2*)&Co[row * N + n0 + c * 2] = v0;
        }
    }
}

// ---------------------------------------------------------------------------
// codebook squared norms (once per call)
// ---------------------------------------------------------------------------
__global__ void cb_norms(const float* __restrict__ codebook, float* __restrict__ cbn)
{
    int i = blockIdx.x * 256 + threadIdx.x;
    if (i < NEMB) {
        float s = 0.f;
#pragma unroll
        for (int k = 0; k < LDIM; ++k) {
            float v = codebook[(size_t)i * LDIM + k];
            s = fmaf(v, v, s);
        }
        cbn[i] = s;
    }
}

// ---------------------------------------------------------------------------
// Fused VQ (score GEMM K=64 + argmin) + latent head (mean/std/z).
// 128 rows per block, 256 threads, codebook processed in 16 chunks of 64.
// Score uses the EXACT reference formula d = (||z||^2 + ||c||^2) - 2*(z.c)
// (the -2*acc term is exact, so fma contraction cannot change the result).
// LDS = 13120 floats = 52.5 KB  (< 64 KB static limit — the round-1 bug).
// ---------------------------------------------------------------------------
__global__ __launch_bounds__(256) void vq_latent(
    const float* __restrict__ midz,      // chunk [M,64]
    const float* __restrict__ codebook,  // [1024,64]
    const float* __restrict__ cbn,       // [1024]
    const float* __restrict__ mean_w, const float* __restrict__ mean_b,
    const float* __restrict__ logstd_w, const float* __restrict__ logstd_b,
    const float* __restrict__ eps,       // chunk [M,64]
    float* __restrict__ mean_out,        // chunk [M,64]
    float* __restrict__ std_out,         // chunk [M,64]
    float* __restrict__ z_out)           // chunk [M,64]
{
    __shared__ float smem[13120];
    float* Zt = smem;                    // [64][132] transposed mid_z  (8448)
    float* Ct = smem + 8448;             // [64][68] transposed cb chunk (4352)
    float* cn = smem + 12800;            // [64]  chunk codebook norms
    float* zn = smem + 12864;            // [128] row norms ||z||^2
    int* sidx = (int*)(smem + 12992);    // [128] argmin per row

    const int tid = threadIdx.x;
    const int m0 = blockIdx.x * 128;
    const int r = tid >> 4;
    const int c = tid & 15;

    // stage Zt (128 rows x 16 f4, transposed)
#pragma unroll
    for (int it = 0; it < 8; ++it) {
        int idx = tid + it * 256;
        int row = idx >> 4;
        int f = idx & 15;
        float4 v = *(const float4*)(midz + (size_t)(m0 + row) * 64 + f * 4);
        Zt[(f * 4 + 0) * 132 + row] = v.x;
        Zt[(f * 4 + 1) * 132 + row] = v.y;
        Zt[(f * 4 + 2) * 132 + row] = v.z;
        Zt[(f * 4 + 3) * 132 + row] = v.w;
    }
    __syncthreads();
    // per-row ||z||^2
    if (tid < 128) {
        float s = 0.f;
#pragma unroll
        for (int k = 0; k < 64; ++k) {
            float v = Zt[k * 132 + tid];
            s = fmaf(v, v, s);
        }
        zn[tid] = s;
    }

    float best[8];
    int bidx[8];
#pragma unroll
    for (int i = 0; i < 8; ++i) { best[i] = 3.4e38f; bidx[i] = 0x7fffffff; }

    for (int ch = 0; ch < 16; ++ch) {
        int e0 = ch * 64;
        __syncthreads();   // prev chunk's Ct/cn readers done; also covers zn write
        // stage Ct: 64 entries x 16 f4 = 1024 f4 -> 4 per thread
#pragma unroll
        for (int it = 0; it < 4; ++it) {
            int idx = tid + it * 256;
            int e = idx >> 4;            // 0..63
            int f = idx & 15;
            float4 v = *(const float4*)(codebook + (size_t)(e0 + e) * 64 + f * 4);
            Ct[(f * 4 + 0) * 68 + e] = v.x;
            Ct[(f * 4 + 1) * 68 + e] = v.y;
            Ct[(f * 4 + 2) * 68 + e] = v.z;
            Ct[(f * 4 + 3) * 68 + e] = v.w;
        }
        if (tid < 64) cn[tid] = cbn[e0 + tid];
        __syncthreads();

        float acc[8][4];
#pragma unroll
        for (int i = 0; i < 8; ++i)
#pragma unroll
            for (int j = 0; j < 4; ++j) acc[i][j] = 0.f;

#pragma unroll 8
        for (int kk = 0; kk < 64; ++kk) {
            float a[8], b[4];
            float4 av0 = *(const float4*)&Zt[kk * 132 + r * 8];
            float4 av1 = *(const float4*)&Zt[kk * 132 + r * 8 + 4];
            a[0] = av0.x; a[1] = av0.y; a[2] = av0.z; a[3] = av0.w;
            a[4] = av1.x; a[5] = av1.y; a[6] = av1.z; a[7] = av1.w;
            float4 bv = *(const float4*)&Ct[kk * 68 + c * 4];
            b[0] = bv.x; b[1] = bv.y; b[2] = bv.z; b[3] = bv.w;
#pragma unroll
            for (int i = 0; i < 8; ++i)
#pragma unroll
                for (int j = 0; j < 4; ++j)
                    acc[i][j] = fmaf(a[i], b[j], acc[i][j]);
        }
#pragma unroll
        for (int i = 0; i < 8; ++i) {
            float zni = zn[r * 8 + i];
#pragma unroll
            for (int j = 0; j < 4; ++j) {
                int e = c * 4 + j;
                float s = (zni + cn[e]) - 2.0f * acc[i][j];
                int gi = e0 + e;
                if (s < best[i] || (s == best[i] && gi < bidx[i])) {
                    best[i] = s;
                    bidx[i] = gi;
                }
            }
        }
    }

    // reduce across the 16 col-threads (contiguous lanes within one wave)
#pragma unroll
    for (int i = 0; i < 8; ++i) {
#pragma unroll
        for (int m = 1; m < 16; m <<= 1) {
            float ob = __shfl_xor(best[i], m, 64);
            int oi = __shfl_xor(bidx[i], m, 64);
            if (ob < best[i] || (ob == best[i] && oi < bidx[i])) {
                best[i] = ob;
                bidx[i] = oi;
            }
        }
    }
    __syncthreads();   // all Zt/Ct/cn/zn reads done before smem reuse
    if (c == 0) {
#pragma unroll
        for (int i = 0; i < 8; ++i) sidx[r * 8 + i] = bidx[i];
    }

    // stage mean_w / logstd_w into (dead) Zt region: mw[64][65], lw[64][65]
    float* mw = smem;
    float* lw = smem + 4160;
#pragma unroll
    for (int it = 0; it < 4; ++it) {
        int idx = tid + it * 256;     // 64 rows x 16 f4
        int k = idx >> 4;
        int f = idx & 15;
        float4 v = *(const float4*)(mean_w + (size_t)k * 64 + f * 4);
        mw[k * 65 + f * 4 + 0] = v.x;
        mw[k * 65 + f * 4 + 1] = v.y;
        mw[k * 65 + f * 4 + 2] = v.z;
        mw[k * 65 + f * 4 + 3] = v.w;
        float4 w = *(const float4*)(logstd_w + (size_t)k * 64 + f * 4);
        lw[k * 65 + f * 4 + 0] = w.x;
        lw[k * 65 + f * 4 + 1] = w.y;
        lw[k * 65 + f * 4 + 2] = w.z;
        lw[k * 65 + f * 4 + 3] = w.w;
    }
    __syncthreads();

    // latent: thread -> (row = tid/2, 32-dim half)
    {
        int row = tid >> 1;
        int d0 = (tid & 1) * 32;
        int e = sidx[row];
        const float* cb = codebook + (size_t)e * 64;
        float mv[32], lv[32];
#pragma unroll
        for (int d = 0; d < 32; ++d) {
            mv[d] = mean_b[d0 + d];
            lv[d] = logstd_b[d0 + d];
        }
        for (int k = 0; k < 64; ++k) {
            float zk = cb[k];
#pragma unroll
            for (int d = 0; d < 32; ++d) {
                mv[d] = fmaf(zk, mw[k * 65 + d0 + d], mv[d]);
                lv[d] = fmaf(zk, lw[k * 65 + d0 + d], lv[d]);
            }
        }
        size_t ro = (size_t)(m0 + row) * 64 + d0;
#pragma unroll
        for (int d = 0; d < 32; ++d) {
            float mean = mv[d];
            float ls = fminf(fmaxf(lv[d], -4.f), 15.f);
            float sd = expf(ls);
            float z = fmaf(sd, eps[ro + d], mean);
            mean_out[ro + d] = mean;
            std_out[ro + d] = sd;
            z_out[ro + d] = z;
        }
    }
}

// ---------------------------------------------------------------------------
extern "C" void kernel_launch(void* const* d_in, const int* in_sizes, int n_in,
                              void* d_out, int out_size, void* d_ws, size_t ws_size,
                              hipStream_t stream)
{
    const float* state    = (const float*)d_in[0];
    const float* action   = (const float*)d_in[1];
    const float* eps      = (const float*)d_in[2];
    const float* enc_w1   = (const float*)d_in[3];
    const float* enc_b1   = (const float*)d_in[4];
    const float* enc_w2   = (const float*)d_in[5];
    const float* enc_b2   = (const float*)d_in[6];
    const float* enc_w3   = (const float*)d_in[7];
    const float* enc_b3   = (const float*)d_in[8];
    const float* mean_w   = (const float*)d_in[9];
    const float* mean_b   = (const float*)d_in[10];
    const float* logstd_w = (const float*)d_in[11];
    const float* logstd_b = (const float*)d_in[12];
    const float* codebook = (const float*)d_in[13];
    const float* dec_w1   = (const float*)d_in[14];
    const float* dec_b1   = (const float*)d_in[15];
    const float* dec_w2   = (const float*)d_in[16];
    const float* dec_b2   = (const float*)d_in[17];
    const float* dec_w3   = (const float*)d_in[18];
    const float* dec_b3   = (const float*)d_in[19];

    float* out = (float*)d_out;
    float* u_out = out;                                    // [B,32]
    float* mean_out = out + (size_t)B_TOTAL * 32;          // [B,64]
    float* std_out = mean_out + (size_t)B_TOTAL * 64;      // [B,64]

    float* ws = (float*)d_ws;
    float* cbn = ws;                                       // [1024]

    // deterministic chunking from ws_size: per row need 2*1024 + 2*64 floats
    size_t avail = ws_size / 4;
    size_t per_row = 2 * 1024 + 2 * 64;
    long maxC = (avail > 2048) ? (long)((avail - 2048) / per_row) : 0;
    int C = (int)(maxC / 128) * 128;
    if (C > B_TOTAL) C = B_TOTAL;
    if (C < 128) C = 128;   // minimum viable; harness ws is expected to cover this

    float* ha = ws + 1024;                  // [C,1024]
    float* hb = ha + (size_t)C * 1024;      // [C,1024]
    float* mz = hb + (size_t)C * 1024;      // [C,64]
    float* zz = mz + (size_t)C * 64;        // [C,64]

    cb_norms<<<dim3((NEMB + 255) / 256), dim3(256), 0, stream>>>(codebook, cbn);

    for (int r0 = 0; r0 < B_TOTAL; r0 += C) {
        int M = (r0 + C <= B_TOTAL) ? C : (B_TOTAL - r0);
        int mt = M / 128;

        // G1: relu(concat(state, action) @ enc_w1 + b1) -> ha
        gemm_f32<128, 0, true><<<dim3(mt, 8), dim3(256), 0, stream>>>(
            state + (size_t)r0 * SDIM, action + (size_t)r0 * ADIM, SDIM,
            SDIM + ADIM, enc_w1, enc_b1, ha, HDIM);
        // G2: relu(ha @ enc_w2 + b2) -> hb
        gemm_f32<128, 0, false><<<dim3(mt, 8), dim3(256), 0, stream>>>(
            ha, nullptr, 0, HDIM, enc_w2, enc_b2, hb, HDIM);
        // G3: relu(hb @ enc_w3 + b3) -> mz
        gemm_f32<64, 0, false><<<dim3(mt, 1), dim3(256), 0, stream>>>(
            hb, nullptr, 0, HDIM, enc_w3, enc_b3, mz, LDIM);
        // VQ + latent head
        vq_latent<<<dim3(mt), dim3(256), 0, stream>>>(
            mz, codebook, cbn, mean_w, mean_b, logstd_w, logstd_b,
            eps + (size_t)r0 * LDIM,
            mean_out + (size_t)r0 * LDIM, std_out + (size_t)r0 * LDIM, zz);
        // G4: relu(concat(state, z) @ dec_w1 + b1) -> ha
        gemm_f32<128, 0, true><<<dim3(mt, 8), dim3(256), 0, stream>>>(
            state + (size_t)r0 * SDIM, zz, SDIM,
            SDIM + LDIM, dec_w1, dec_b1, ha, HDIM);
        // G5: relu(ha @ dec_w2 + b2) -> hb
        gemm_f32<128, 0, false><<<dim3(mt, 8), dim3(256), 0, stream>>>(
            ha, nullptr, 0, HDIM, dec_w2, dec_b2, hb, HDIM);
        // G6: tanh(hb @ dec_w3 + b3) -> u
        gemm_f32<32, 1, false><<<dim3(mt, 1), dim3(256), 0, stream>>>(
            hb, nullptr, 0, HDIM, dec_w3, dec_b3, u_out + (size_t)r0 * ADIM, ADIM);
    }
}

// Round 3
// 2995.456 us; speedup vs baseline: 1.5209x; 1.5209x over previous
//
#include <hip/hip_runtime.h>
#include <cstdint>
#include <cstddef>

#define B_TOTAL 65536
#define SDIM 64
#define ADIM 32
#define LDIM 64
#define HDIM 1024
#define NEMB 1024

typedef __attribute__((ext_vector_type(8))) short short8;
typedef __attribute__((ext_vector_type(4))) float f32x4;

__device__ inline unsigned short f2bf(float f) {
    unsigned int u = __float_as_uint(f);
    u += 0x7fffu + ((u >> 16) & 1u);
    return (unsigned short)(u >> 16);
}
__device__ inline float bf2f(unsigned short s) {
    return __uint_as_float(((unsigned int)s) << 16);
}

// ---------------------------------------------------------------------------
// fp32 GEMM (unchanged, passing): encoder G1/G2/G3.
// ---------------------------------------------------------------------------
template <int BN, int ACT, bool CONCAT>
__global__ __launch_bounds__(256) void gemm_f32(
    const float* __restrict__ A0, const float* __restrict__ A1, int a0w,
    int K, const float* __restrict__ W, const float* __restrict__ bias,
    float* __restrict__ Co, int N)
{
    constexpr int TN = BN / 16;
    __shared__ float At[16][132];
    __shared__ float Bt[16][BN + 4];

    const int tid = threadIdx.x;
    const int m0 = blockIdx.x * 128;
    const int n0 = blockIdx.y * BN;
    const int r = tid >> 4;
    const int c = tid & 15;
    const int a1w = K - a0w;

    float acc[8][TN];
#pragma unroll
    for (int i = 0; i < 8; ++i)
#pragma unroll
        for (int j = 0; j < TN; ++j) acc[i][j] = 0.f;

    for (int k0 = 0; k0 < K; k0 += 16) {
#pragma unroll
        for (int it = 0; it < 2; ++it) {
            int idx = tid + it * 256;
            int row = idx >> 2;
            int lf = idx & 3;
            int col = k0 + lf * 4;
            const float* src;
            if (CONCAT) {
                if (col < a0w) src = A0 + (size_t)(m0 + row) * a0w + col;
                else           src = A1 + (size_t)(m0 + row) * a1w + (col - a0w);
            } else {
                src = A0 + (size_t)(m0 + row) * K + col;
            }
            float4 v = *(const float4*)src;
            At[lf * 4 + 0][row] = v.x;
            At[lf * 4 + 1][row] = v.y;
            At[lf * 4 + 2][row] = v.z;
            At[lf * 4 + 3][row] = v.w;
        }
        constexpr int NF4 = BN / 4;
        constexpr int NEL = 16 * NF4;
        if constexpr (NEL >= 256) {
#pragma unroll
            for (int it = 0; it < NEL / 256; ++it) {
                int idx = tid + it * 256;
                int kk = idx / NF4;
                int f = idx % NF4;
                float4 v = *(const float4*)(W + (size_t)(k0 + kk) * N + n0 + f * 4);
                *(float4*)&Bt[kk][f * 4] = v;
            }
        } else {
            if (tid < NEL) {
                int kk = tid / NF4;
                int f = tid % NF4;
                float4 v = *(const float4*)(W + (size_t)(k0 + kk) * N + n0 + f * 4);
                *(float4*)&Bt[kk][f * 4] = v;
            }
        }
        __syncthreads();

#pragma unroll
        for (int kk = 0; kk < 16; ++kk) {
            float a[8];
            float4 av0 = *(const float4*)&At[kk][r * 8];
            float4 av1 = *(const float4*)&At[kk][r * 8 + 4];
            a[0] = av0.x; a[1] = av0.y; a[2] = av0.z; a[3] = av0.w;
            a[4] = av1.x; a[5] = av1.y; a[6] = av1.z; a[7] = av1.w;
            float b[TN];
            if constexpr (BN == 128) {
                float4 b0 = *(const float4*)&Bt[kk][c * 4];
                float4 b1 = *(const float4*)&Bt[kk][64 + c * 4];
                b[0] = b0.x; b[1] = b0.y; b[2] = b0.z; b[3] = b0.w;
                b[4] = b1.x; b[5] = b1.y; b[6] = b1.z; b[7] = b1.w;
            } else if constexpr (BN == 64) {
                float4 b0 = *(const float4*)&Bt[kk][c * 4];
                b[0] = b0.x; b[1] = b0.y; b[2] = b0.z; b[3] = b0.w;
            } else {
                float2 b0 = *(const float2*)&Bt[kk][c * 2];
                b[0] = b0.x; b[1] = b0.y;
            }
#pragma unroll
            for (int i = 0; i < 8; ++i)
#pragma unroll
                for (int j = 0; j < TN; ++j)
                    acc[i][j] = fmaf(a[i], b[j], acc[i][j]);
        }
        __syncthreads();
    }

#pragma unroll
    for (int i = 0; i < 8; ++i) {
        size_t row = (size_t)(m0 + r * 8 + i);
        if constexpr (BN == 128) {
            float4 v0, v1;
            float e[8];
#pragma unroll
            for (int j = 0; j < 8; ++j) {
                int col = (j < 4) ? (c * 4 + j) : (64 + c * 4 + (j - 4));
                float v = acc[i][j] + bias[n0 + col];
                if (ACT == 0) v = fmaxf(v, 0.f);
                else if (ACT == 1) v = tanhf(v);
                e[j] = v;
            }
            v0.x = e[0]; v0.y = e[1]; v0.z = e[2]; v0.w = e[3];
            v1.x = e[4]; v1.y = e[5]; v1.z = e[6]; v1.w = e[7];
            *(float4*)&Co[row * N + n0 + c * 4] = v0;
            *(float4*)&Co[row * N + n0 + 64 + c * 4] = v1;
        } else if constexpr (BN == 64) {
            float4 v0;
            float e[4];
#pragma unroll
            for (int j = 0; j < 4; ++j) {
                float v = acc[i][j] + bias[n0 + c * 4 + j];
                if (ACT == 0) v = fmaxf(v, 0.f);
                else if (ACT == 1) v = tanhf(v);
                e[j] = v;
            }
            v0.x = e[0]; v0.y = e[1]; v0.z = e[2]; v0.w = e[3];
            *(float4*)&Co[row * N + n0 + c * 4] = v0;
        } else {
            float2 v0;
            float e[2];
#pragma unroll
            for (int j = 0; j < 2; ++j) {
                float v = acc[i][j] + bias[n0 + c * 2 + j];
                if (ACT == 0) v = fmaxf(v, 0.f);
                else if (ACT == 1) v = tanhf(v);
                e[j] = v;
            }
            v0.x = e[0]; v0.y = e[1];
            *(float2*)&Co[row * N + n0 + c * 2] = v0;
        }
    }
}

// ---------------------------------------------------------------------------
__global__ void cb_norms(const float* __restrict__ codebook, float* __restrict__ cbn)
{
    int i = blockIdx.x * 256 + threadIdx.x;
    if (i < NEMB) {
        float s = 0.f;
#pragma unroll
        for (int k = 0; k < LDIM; ++k) {
            float v = codebook[(size_t)i * LDIM + k];
            s = fmaf(v, v, s);
        }
        cbn[i] = s;
    }
}

// ---------------------------------------------------------------------------
// Weight pre-transform: W[K][N] fp32 -> bf16 plane(s) in MFMA-B-ready layout.
// Plane layout: for (nb, ks): contiguous block of 4*BN*8 bf16 at
//   off = ((nb*KS + ks)*BN*32), inner (kb*BN + n)*8 + j, where k = ks*32+kb*8+j.
// NT==3 additionally writes lo plane (w - bf16(w)).
// ---------------------------------------------------------------------------
template <int NT, int BN>
__global__ __launch_bounds__(256) void w_xform(
    const float* __restrict__ W, int K, int N,
    unsigned short* __restrict__ Ph, unsigned short* __restrict__ Pl)
{
    __shared__ float Ws[32][BN + 4];
    const int tid = threadIdx.x;
    const int ks = blockIdx.x, nb = blockIdx.y;
    const int k0 = ks * 32, n0 = nb * BN;
    constexpr int LT = 32 * (BN / 4);   // float4 load tasks
#pragma unroll
    for (int it = 0; it < (LT + 255) / 256; ++it) {
        int idx = tid + it * 256;
        if (LT % 256 == 0 || idx < LT) {
            int k = idx / (BN / 4);
            int nf = idx % (BN / 4);
            *(f32x4*)&Ws[k][nf * 4] =
                *(const f32x4*)&W[(size_t)(k0 + k) * N + n0 + nf * 4];
        }
    }
    __syncthreads();
    const int KS = K >> 5;
    size_t bo = ((size_t)nb * KS + ks) * (BN * 32);
    constexpr int WT = BN * 4;          // 16B write tasks (n-fast)
#pragma unroll
    for (int it = 0; it < (WT + 255) / 256; ++it) {
        int idx = tid + it * 256;
        if (WT % 256 == 0 || idx < WT) {
            int kb = idx / BN;
            int n = idx % BN;
            short8 h, l;
#pragma unroll
            for (int j = 0; j < 8; ++j) {
                float x = Ws[kb * 8 + j][n];
                unsigned short hb_ = f2bf(x);
                h[j] = (short)hb_;
                if (NT == 3) l[j] = (short)f2bf(x - bf2f(hb_));
            }
            *(short8*)&Ph[bo + (size_t)idx * 8] = h;
            if (NT == 3) *(short8*)&Pl[bo + (size_t)idx * 8] = l;
        }
    }
}

// ---------------------------------------------------------------------------
// BF16 MFMA GEMM: C[M,N] = act(A[M,K] @ W + bias), A = bf16 plane [row][K],
// W = pre-transformed plane(s). 128-row tile x BN, 256 threads (4 waves).
// 16x16x32 MFMA; A-frag: row=lane&15, k=(lane>>4)*8+j; B-frag: col=lane&15.
// C/D: col=lane&15, row=(lane>>4)*4+reg  [guide-verified m89/m91].
// OUT: 0=bf16 hi+lo planes, 1=bf16 plane, 2=fp32. ACT: 0=relu, 1=tanh.
// NT: 1 = plain bf16; 3 = split (A=hi+lo, W=hi+lo, 3 terms).
// ---------------------------------------------------------------------------
template <int NT, int BN, int OUT, int ACT>
__global__ __launch_bounds__(256, 2) void mfma_gemm(
    const unsigned short* __restrict__ Ah_g, const unsigned short* __restrict__ Al_g,
    int K,
    const unsigned short* __restrict__ Wh, const unsigned short* __restrict__ Wl,
    const float* __restrict__ bias,
    void* __restrict__ out0, void* __restrict__ out1, int NTOT)
{
    constexpr int NWC = (BN == 128) ? 2 : 1;
    constexpr int WM = (BN == 128) ? 4 : 2;
    constexpr int WN = (BN == 32) ? 2 : 4;

    __shared__ unsigned short smem[16384];   // 32 KB
    unsigned short* Ah = smem;                               // 4096
    unsigned short* Al = smem + 4096;                        // NT3 only
    unsigned short* Bh = smem + (NT == 3 ? 8192 : 4096);     // 4*BN*8
    unsigned short* Bl = Bh + 4 * BN * 8;                    // NT3 only

    const int tid = threadIdx.x;
    const int m0 = blockIdx.x * 128;
    const int nb = blockIdx.y;
    const int n0 = nb * BN;
    const int w = tid >> 6, lane = tid & 63;
    const int g = lane >> 4, lr = lane & 15;
    const int wrow0 = (w / NWC) * (WM * 16);
    const int wcol0 = (w % NWC) * (WN * 16);
    const int KS = K >> 5;

    f32x4 acc[WM][WN];
#pragma unroll
    for (int m = 0; m < WM; ++m)
#pragma unroll
        for (int n = 0; n < WN; ++n) {
            acc[m][n][0] = 0.f; acc[m][n][1] = 0.f;
            acc[m][n][2] = 0.f; acc[m][n][3] = 0.f;
        }

    for (int ks = 0; ks < KS; ++ks) {
        __syncthreads();   // previous step's fragment reads done
        // ---- stage A (reg copy, bf16 plane row-major width K) ----
#pragma unroll
        for (int it = 0; it < 2; ++it) {
            int t2 = tid + it * 256;          // 512 tasks
            int row = t2 >> 2, kb = t2 & 3;
            size_t go = (size_t)(m0 + row) * K + ks * 32 + kb * 8;
            *(short8*)&Ah[(kb * 128 + row) * 8] = *(const short8*)&Ah_g[go];
            if constexpr (NT == 3)
                *(short8*)&Al[(kb * 128 + row) * 8] = *(const short8*)&Al_g[go];
        }
        // ---- stage B (linear copy from pre-transformed plane) ----
        {
            size_t bo = ((size_t)nb * KS + ks) * (BN * 32);
            constexpr int BT = 4 * BN;        // 16B tasks
            if constexpr (BT >= 256) {
#pragma unroll
                for (int it = 0; it < BT / 256; ++it) {
                    int t2 = tid + it * 256;
                    *(short8*)&Bh[t2 * 8] = *(const short8*)&Wh[bo + (size_t)t2 * 8];
                    if constexpr (NT == 3)
                        *(short8*)&Bl[t2 * 8] = *(const short8*)&Wl[bo + (size_t)t2 * 8];
                }
            } else {
                if (tid < BT) {
                    *(short8*)&Bh[tid * 8] = *(const short8*)&Wh[bo + (size_t)tid * 8];
                    if constexpr (NT == 3)
                        *(short8*)&Bl[tid * 8] = *(const short8*)&Wl[bo + (size_t)tid * 8];
                }
            }
        }
        __syncthreads();

        // ---- fragments + MFMA ----
        short8 ah[WM], bh[WN];
        short8 al[WM], bl[WN];
#pragma unroll
        for (int m = 0; m < WM; ++m) {
            int ro = (g << 7) + wrow0 + m * 16 + lr;
            ah[m] = *(const short8*)&Ah[ro * 8];
            if constexpr (NT == 3) al[m] = *(const short8*)&Al[ro * 8];
        }
#pragma unroll
        for (int n = 0; n < WN; ++n) {
            int co = g * BN + wcol0 + n * 16 + lr;
            bh[n] = *(const short8*)&Bh[co * 8];
            if constexpr (NT == 3) bl[n] = *(const short8*)&Bl[co * 8];
        }
#pragma unroll
        for (int m = 0; m < WM; ++m)
#pragma unroll
            for (int n = 0; n < WN; ++n) {
                acc[m][n] = __builtin_amdgcn_mfma_f32_16x16x32_bf16(
                    ah[m], bh[n], acc[m][n], 0, 0, 0);
                if constexpr (NT == 3) {
                    acc[m][n] = __builtin_amdgcn_mfma_f32_16x16x32_bf16(
                        ah[m], bl[n], acc[m][n], 0, 0, 0);
                    acc[m][n] = __builtin_amdgcn_mfma_f32_16x16x32_bf16(
                        al[m], bh[n], acc[m][n], 0, 0, 0);
                }
            }
    }

    // ---- epilogue: bias + act, LDS transpose, coalesced stores ----
    float bv[WN];
#pragma unroll
    for (int n = 0; n < WN; ++n) bv[n] = bias[n0 + wcol0 + n * 16 + lr];

    unsigned short* Sb = smem;
    float* Sf = (float*)smem;
    constexpr int NPASS = (OUT == 0) ? 2 : 1;

#pragma unroll
    for (int p = 0; p < NPASS; ++p) {
        __syncthreads();   // LDS free (k-loop reads / previous pass stores done)
#pragma unroll
        for (int m = 0; m < WM; ++m)
#pragma unroll
            for (int n = 0; n < WN; ++n)
#pragma unroll
                for (int q = 0; q < 4; ++q) {
                    int rl = wrow0 + m * 16 + g * 4 + q;
                    int cl = wcol0 + n * 16 + lr;
                    float x = acc[m][n][q] + bv[n];
                    if (ACT == 0) x = fmaxf(x, 0.f);
                    else x = tanhf(x);
                    if constexpr (OUT == 2) {
                        Sf[rl * BN + cl] = x;
                    } else {
                        unsigned short hb_ = f2bf(x);
                        Sb[rl * BN + cl] = (p == 0) ? hb_ : f2bf(x - bf2f(hb_));
                    }
                }
        __syncthreads();
        if constexpr (OUT == 2) {
            constexpr int SL = BN / 4;                 // float4 slots per row
#pragma unroll
            for (int it = 0; it < (128 * SL) / 256; ++it) {
                int idx = tid + it * 256;
                int row = idx / SL, sl = idx % SL;
                *(f32x4*)((float*)out0 + (size_t)(m0 + row) * NTOT + n0 + sl * 4)
                    = *(const f32x4*)&Sf[row * BN + sl * 4];
            }
        } else {
            constexpr int SL = BN / 8;                 // short8 slots per row
            unsigned short* dst = (unsigned short*)((p == 0) ? out0 : out1);
#pragma unroll
            for (int it = 0; it < (128 * SL) / 256; ++it) {
                int idx = tid + it * 256;
                int row = idx / SL, sl = idx % SL;
                *(short8*)&dst[(size_t)(m0 + row) * NTOT + n0 + sl * 8]
                    = *(const short8*)&Sb[row * BN + sl * 8];
            }
        }
    }
}

// ---------------------------------------------------------------------------
// xz plane: cols 0..63 = bf16(state) for the decoder concat input.
// ---------------------------------------------------------------------------
__global__ void xz_pre(const float* __restrict__ state, unsigned short* __restrict__ xz)
{
    int idx = blockIdx.x * 256 + threadIdx.x;
    int row = idx >> 4, q = idx & 15;
    f32x4 v = *(const f32x4*)&state[(size_t)row * 64 + q * 4];
    unsigned short o[4];
    o[0] = f2bf(v[0]); o[1] = f2bf(v[1]); o[2] = f2bf(v[2]); o[3] = f2bf(v[3]);
    *(uint2*)&xz[(size_t)row * 128 + q * 4] = *(uint2*)o;
}

// ---------------------------------------------------------------------------
// Fused VQ + latent head (fp32 argmin preserved).  z now emitted as bf16
// into xz plane cols 64..127 (decoder input).
// ---------------------------------------------------------------------------
__global__ __launch_bounds__(256) void vq_latent(
    const float* __restrict__ midz,
    const float* __restrict__ codebook,
    const float* __restrict__ cbn,
    const float* __restrict__ mean_w, const float* __restrict__ mean_b,
    const float* __restrict__ logstd_w, const float* __restrict__ logstd_b,
    const float* __restrict__ eps,
    float* __restrict__ mean_out,
    float* __restrict__ std_out,
    unsigned short* __restrict__ xz)
{
    __shared__ float smem[13120];
    float* Zt = smem;
    float* Ct = smem + 8448;
    float* cn = smem + 12800;
    float* zn = smem + 12864;
    int* sidx = (int*)(smem + 12992);

    const int tid = threadIdx.x;
    const int m0 = blockIdx.x * 128;
    const int r = tid >> 4;
    const int c = tid & 15;

#pragma unroll
    for (int it = 0; it < 8; ++it) {
        int idx = tid + it * 256;
        int row = idx >> 4;
        int f = idx & 15;
        float4 v = *(const float4*)(midz + (size_t)(m0 + row) * 64 + f * 4);
        Zt[(f * 4 + 0) * 132 + row] = v.x;
        Zt[(f * 4 + 1) * 132 + row] = v.y;
        Zt[(f * 4 + 2) * 132 + row] = v.z;
        Zt[(f * 4 + 3) * 132 + row] = v.w;
    }
    __syncthreads();
    if (tid < 128) {
        float s = 0.f;
#pragma unroll
        for (int k = 0; k < 64; ++k) {
            float v = Zt[k * 132 + tid];
            s = fmaf(v, v, s);
        }
        zn[tid] = s;
    }

    float best[8];
    int bidx[8];
#pragma unroll
    for (int i = 0; i < 8; ++i) { best[i] = 3.4e38f; bidx[i] = 0x7fffffff; }

    for (int ch = 0; ch < 16; ++ch) {
        int e0 = ch * 64;
        __syncthreads();
#pragma unroll
        for (int it = 0; it < 4; ++it) {
            int idx = tid + it * 256;
            int e = idx >> 4;
            int f = idx & 15;
            float4 v = *(const float4*)(codebook + (size_t)(e0 + e) * 64 + f * 4);
            Ct[(f * 4 + 0) * 68 + e] = v.x;
            Ct[(f * 4 + 1) * 68 + e] = v.y;
            Ct[(f * 4 + 2) * 68 + e] = v.z;
            Ct[(f * 4 + 3) * 68 + e] = v.w;
        }
        if (tid < 64) cn[tid] = cbn[e0 + tid];
        __syncthreads();

        float acc[8][4];
#pragma unroll
        for (int i = 0; i < 8; ++i)
#pragma unroll
            for (int j = 0; j < 4; ++j) acc[i][j] = 0.f;

#pragma unroll 8
        for (int kk = 0; kk < 64; ++kk) {
            float a[8], b[4];
            float4 av0 = *(const float4*)&Zt[kk * 132 + r * 8];
            float4 av1 = *(const float4*)&Zt[kk * 132 + r * 8 + 4];
            a[0] = av0.x; a[1] = av0.y; a[2] = av0.z; a[3] = av0.w;
            a[4] = av1.x; a[5] = av1.y; a[6] = av1.z; a[7] = av1.w;
            float4 bv = *(const float4*)&Ct[kk * 68 + c * 4];
            b[0] = bv.x; b[1] = bv.y; b[2] = bv.z; b[3] = bv.w;
#pragma unroll
            for (int i = 0; i < 8; ++i)
#pragma unroll
                for (int j = 0; j < 4; ++j)
                    acc[i][j] = fmaf(a[i], b[j], acc[i][j]);
        }
#pragma unroll
        for (int i = 0; i < 8; ++i) {
            float zni = zn[r * 8 + i];
#pragma unroll
            for (int j = 0; j < 4; ++j) {
                int e = c * 4 + j;
                float s = (zni + cn[e]) - 2.0f * acc[i][j];
                int gi = e0 + e;
                if (s < best[i] || (s == best[i] && gi < bidx[i])) {
                    best[i] = s;
                    bidx[i] = gi;
                }
            }
        }
    }

#pragma unroll
    for (int i = 0; i < 8; ++i) {
#pragma unroll
        for (int m = 1; m < 16; m <<= 1) {
            float ob = __shfl_xor(best[i], m, 64);
            int oi = __shfl_xor(bidx[i], m, 64);
            if (ob < best[i] || (ob == best[i] && oi < bidx[i])) {
                best[i] = ob;
                bidx[i] = oi;
            }
        }
    }
    __syncthreads();
    if (c == 0) {
#pragma unroll
        for (int i = 0; i < 8; ++i) sidx[r * 8 + i] = bidx[i];
    }

    float* mw = smem;
    float* lw = smem + 4160;
#pragma unroll
    for (int it = 0; it < 4; ++it) {
        int idx = tid + it * 256;
        int k = idx >> 4;
        int f = idx & 15;
        float4 v = *(const float4*)(mean_w + (size_t)k * 64 + f * 4);
        mw[k * 65 + f * 4 + 0] = v.x;
        mw[k * 65 + f * 4 + 1] = v.y;
        mw[k * 65 + f * 4 + 2] = v.z;
        mw[k * 65 + f * 4 + 3] = v.w;
        float4 w2 = *(const float4*)(logstd_w + (size_t)k * 64 + f * 4);
        lw[k * 65 + f * 4 + 0] = w2.x;
        lw[k * 65 + f * 4 + 1] = w2.y;
        lw[k * 65 + f * 4 + 2] = w2.z;
        lw[k * 65 + f * 4 + 3] = w2.w;
    }
    __syncthreads();

    {
        int row = tid >> 1;
        int d0 = (tid & 1) * 32;
        int e = sidx[row];
        const float* cb = codebook + (size_t)e * 64;
        float mv[32], lv[32];
#pragma unroll
        for (int d = 0; d < 32; ++d) {
            mv[d] = mean_b[d0 + d];
            lv[d] = logstd_b[d0 + d];
        }
        for (int k = 0; k < 64; ++k) {
            float zk = cb[k];
#pragma unroll
            for (int d = 0; d < 32; ++d) {
                mv[d] = fmaf(zk, mw[k * 65 + d0 + d], mv[d]);
                lv[d] = fmaf(zk, lw[k * 65 + d0 + d], lv[d]);
            }
        }
        size_t ro = (size_t)(m0 + row) * 64 + d0;
        size_t xo = (size_t)(m0 + row) * 128 + 64 + d0;
#pragma unroll
        for (int d = 0; d < 32; ++d) {
            float mean = mv[d];
            float ls = fminf(fmaxf(lv[d], -4.f), 15.f);
            float sd = expf(ls);
            float z = fmaf(sd, eps[ro + d], mean);
            mean_out[ro + d] = mean;
            std_out[ro + d] = sd;
            xz[xo + d] = f2bf(z);
        }
    }
}

// ---------------------------------------------------------------------------
extern "C" void kernel_launch(void* const* d_in, const int* in_sizes, int n_in,
                              void* d_out, int out_size, void* d_ws, size_t ws_size,
                              hipStream_t stream)
{
    const float* state    = (const float*)d_in[0];
    const float* action   = (const float*)d_in[1];
    const float* eps      = (const float*)d_in[2];
    const float* enc_w1   = (const float*)d_in[3];
    const float* enc_b1   = (const float*)d_in[4];
    const float* enc_w2   = (const float*)d_in[5];
    const float* enc_b2   = (const float*)d_in[6];
    const float* enc_w3   = (const float*)d_in[7];
    const float* enc_b3   = (const float*)d_in[8];
    const float* mean_w   = (const float*)d_in[9];
    const float* mean_b   = (const float*)d_in[10];
    const float* logstd_w = (const float*)d_in[11];
    const float* logstd_b = (const float*)d_in[12];
    const float* codebook = (const float*)d_in[13];
    const float* dec_w1   = (const float*)d_in[14];
    const float* dec_b1   = (const float*)d_in[15];
    const float* dec_w2   = (const float*)d_in[16];
    const float* dec_b2   = (const float*)d_in[17];
    const float* dec_w3   = (const float*)d_in[18];
    const float* dec_b3   = (const float*)d_in[19];

    float* out = (float*)d_out;
    float* u_out = out;
    float* mean_out = out + (size_t)B_TOTAL * 32;
    float* std_out = mean_out + (size_t)B_TOTAL * 64;

    // ---- fixed ws region: cbn + pre-transformed decoder weights ----
    char* base = (char*)d_ws;
    float* cbn = (float*)base;                               // 4 KB
    unsigned short* W4h = (unsigned short*)(base + 4096);            // 128*1024*2  = 256 KB
    unsigned short* W5h = (unsigned short*)(base + 4096 + 262144);   // 1024*1024*2 = 2 MB
    unsigned short* W6h = (unsigned short*)(base + 4096 + 262144 + 2097152); // 64 KB
    const size_t FIXED = 4096 + 262144 + 2097152 + 65536;    // 2428928 B

    // ---- chunking: per-row bytes = ha 4096 + hb 4096 + mz 256 + xz 256 ----
    const size_t per_row = 8704;
    long maxC = (ws_size > FIXED) ? (long)((ws_size - FIXED) / per_row) : 0;
    int C = (int)(maxC / 128) * 128;
    if (C > B_TOTAL) C = B_TOTAL;
    if (C < 128) C = 128;

    float* ha = (float*)(base + FIXED);            // [C,1024] f32 (reused: hcH bf16)
    float* hb = ha + (size_t)C * 1024;             // [C,1024] f32 (reused: hdH bf16)
    float* mz = hb + (size_t)C * 1024;             // [C,64]   f32
    unsigned short* xz = (unsigned short*)(mz + (size_t)C * 64); // [C,128] bf16
    unsigned short* hcH = (unsigned short*)ha;     // [C,1024] bf16
    unsigned short* hdH = (unsigned short*)hb;     // [C,1024] bf16

    // ---- once per call ----
    cb_norms<<<dim3((NEMB + 255) / 256), dim3(256), 0, stream>>>(codebook, cbn);
    w_xform<1, 128><<<dim3(4, 8), dim3(256), 0, stream>>>(dec_w1, 128, 1024, W4h, nullptr);
    w_xform<1, 128><<<dim3(32, 8), dim3(256), 0, stream>>>(dec_w2, 1024, 1024, W5h, nullptr);
    w_xform<1, 32><<<dim3(32, 1), dim3(256), 0, stream>>>(dec_w3, 1024, 32, W6h, nullptr);

    for (int r0 = 0; r0 < B_TOTAL; r0 += C) {
        int M = (r0 + C <= B_TOTAL) ? C : (B_TOTAL - r0);
        int mt = M / 128;

        // encoder (fp32, unchanged)
        gemm_f32<128, 0, true><<<dim3(mt, 8), dim3(256), 0, stream>>>(
            state + (size_t)r0 * SDIM, action + (size_t)r0 * ADIM, SDIM,
            SDIM + ADIM, enc_w1, enc_b1, ha, HDIM);
        gemm_f32<128, 0, false><<<dim3(mt, 8), dim3(256), 0, stream>>>(
            ha, nullptr, 0, HDIM, enc_w2, enc_b2, hb, HDIM);
        gemm_f32<64, 0, false><<<dim3(mt, 1), dim3(256), 0, stream>>>(
            hb, nullptr, 0, HDIM, enc_w3, enc_b3, mz, LDIM);

        // xz state half (after G1/G2 no longer need... independent buffer anyway)
        xz_pre<<<dim3(M / 16), dim3(256), 0, stream>>>(state + (size_t)r0 * SDIM, xz);

        // VQ + latent (fp32 argmin), z -> xz cols 64..127
        vq_latent<<<dim3(mt), dim3(256), 0, stream>>>(
            mz, codebook, cbn, mean_w, mean_b, logstd_w, logstd_b,
            eps + (size_t)r0 * LDIM,
            mean_out + (size_t)r0 * LDIM, std_out + (size_t)r0 * LDIM, xz);

        // decoder (bf16 MFMA)
        mfma_gemm<1, 128, 1, 0><<<dim3(mt, 8), dim3(256), 0, stream>>>(
            xz, nullptr, 128, W4h, nullptr, dec_b1, hcH, nullptr, 1024);
        mfma_gemm<1, 128, 1, 0><<<dim3(mt, 8), dim3(256), 0, stream>>>(
            hcH, nullptr, 1024, W5h, nullptr, dec_b2, hdH, nullptr, 1024);
        mfma_gemm<1, 32, 2, 1><<<dim3(mt, 1), dim3(256), 0, stream>>>(
            hdH, nullptr, 1024, W6h, nullptr, dec_b3,
            u_out + (size_t)r0 * ADIM, nullptr, 32);
    }
}

// Round 4
// 2326.280 us; speedup vs baseline: 1.9584x; 1.2877x over previous
//
#include <hip/hip_runtime.h>
#include <cstdint>
#include <cstddef>

#define B_TOTAL 65536
#define SDIM 64
#define ADIM 32
#define LDIM 64
#define HDIM 1024
#define NEMB 1024
#define TAU 0.125f

typedef __attribute__((ext_vector_type(8))) short short8;
typedef __attribute__((ext_vector_type(4))) float f32x4;

__device__ inline unsigned short f2bf(float f) {
    unsigned int u = __float_as_uint(f);
    u += 0x7fffu + ((u >> 16) & 1u);
    return (unsigned short)(u >> 16);
}
__device__ inline float bf2f(unsigned short s) {
    return __uint_as_float(((unsigned int)s) << 16);
}

// async global->LDS, 16B per lane; LDS dest = wave-uniform base + lane*16.
__device__ inline void gload16(const unsigned short* g, unsigned short* l) {
    __builtin_amdgcn_global_load_lds(
        (__attribute__((address_space(1))) void*)(g),
        (__attribute__((address_space(3))) void*)(l), 16, 0, 0);
}

// ---------------------------------------------------------------------------
// codebook squared norms
// ---------------------------------------------------------------------------
__global__ void cb_norms(const float* __restrict__ codebook, float* __restrict__ cbn)
{
    int i = blockIdx.x * 256 + threadIdx.x;
    if (i < NEMB) {
        float s = 0.f;
#pragma unroll
        for (int k = 0; k < LDIM; ++k) {
            float v = codebook[(size_t)i * LDIM + k];
            s = fmaf(v, v, s);
        }
        cbn[i] = s;
    }
}

__global__ void zero_ctr(int* ctr) { if (threadIdx.x == 0) *ctr = 0; }

// ---------------------------------------------------------------------------
// Weight pre-transform: W[K][N] fp32 -> bf16 plane(s), MFMA-B-ready layout.
// Block (nb,ks) of 4*BN*8 bf16 at off ((nb*KS+ks)*BN*32); task idx=(kb*BN+n),
// 8 bf16 k-contiguous (k = ks*32+kb*8+j).  NT==3 adds lo plane (w - bf16(w)).
// ---------------------------------------------------------------------------
template <int NT, int BN>
__global__ __launch_bounds__(256) void w_xform(
    const float* __restrict__ W, int K, int N,
    unsigned short* __restrict__ Ph, unsigned short* __restrict__ Pl)
{
    __shared__ float Ws[32][BN + 4];
    const int tid = threadIdx.x;
    const int ks = blockIdx.x, nb = blockIdx.y;
    const int k0 = ks * 32, n0 = nb * BN;
    constexpr int LT = 32 * (BN / 4);
#pragma unroll
    for (int it = 0; it < (LT + 255) / 256; ++it) {
        int idx = tid + it * 256;
        if (LT % 256 == 0 || idx < LT) {
            int k = idx / (BN / 4);
            int nf = idx % (BN / 4);
            *(f32x4*)&Ws[k][nf * 4] =
                *(const f32x4*)&W[(size_t)(k0 + k) * N + n0 + nf * 4];
        }
    }
    __syncthreads();
    const int KS = K >> 5;
    size_t bo = ((size_t)nb * KS + ks) * (BN * 32);
    constexpr int WT = BN * 4;
#pragma unroll
    for (int it = 0; it < (WT + 255) / 256; ++it) {
        int idx = tid + it * 256;
        if (WT % 256 == 0 || idx < WT) {
            int kb = idx / BN;
            int n = idx % BN;
            short8 h, l;
#pragma unroll
            for (int j = 0; j < 8; ++j) {
                float x = Ws[kb * 8 + j][n];
                unsigned short hb_ = f2bf(x);
                h[j] = (short)hb_;
                if (NT == 3) l[j] = (short)f2bf(x - bf2f(hb_));
            }
            *(short8*)&Ph[bo + (size_t)idx * 8] = h;
            if (NT == 3) *(short8*)&Pl[bo + (size_t)idx * 8] = l;
        }
    }
}

// ---------------------------------------------------------------------------
// BF16 MFMA GEMM via global_load_lds staging.
// A plane row-major [row][K] bf16 (hi, + lo if NT==3); W pre-transformed.
// LDS layouts identical to round-3 (frag reads unchanged, conflict-free);
// staging permutation carried by per-lane GLOBAL addresses.
// OUT: 0=bf16 hi+lo planes, 1=bf16 plane, 2=fp32. ACT: 0=relu, 1=tanh.
// ---------------------------------------------------------------------------
template <int NT, int BN, int OUT, int ACT>
__global__ __launch_bounds__(256, 2) void mfma_gemm(
    const unsigned short* __restrict__ Ah_g, const unsigned short* __restrict__ Al_g,
    int K,
    const unsigned short* __restrict__ Wh, const unsigned short* __restrict__ Wl,
    const float* __restrict__ bias,
    void* __restrict__ out0, void* __restrict__ out1, int NTOT)
{
    constexpr int NWC = (BN == 128) ? 2 : 1;
    constexpr int WM = (BN == 128) ? 4 : 2;
    constexpr int WN = (BN == 32) ? 2 : 4;

    __shared__ unsigned short smem[16384];   // 32 KB
    unsigned short* Ah = smem;                               // 4096 shorts
    unsigned short* Al = smem + 4096;                        // NT3 only
    unsigned short* Bh = smem + (NT == 3 ? 8192 : 4096);     // 4*BN*8
    unsigned short* Bl = Bh + 4 * BN * 8;                    // NT3 only

    const int tid = threadIdx.x;
    const int m0 = blockIdx.x * 128;
    const int nb = blockIdx.y;
    const int n0 = nb * BN;
    const int w = tid >> 6, lane = tid & 63;
    const int g = lane >> 4, lr = lane & 15;
    const int wrow0 = (w / NWC) * (WM * 16);
    const int wcol0 = (w % NWC) * (WN * 16);
    const int KS = K >> 5;

    f32x4 acc[WM][WN];
#pragma unroll
    for (int m = 0; m < WM; ++m)
#pragma unroll
        for (int n = 0; n < WN; ++n) {
            acc[m][n][0] = 0.f; acc[m][n][1] = 0.f;
            acc[m][n][2] = 0.f; acc[m][n][3] = 0.f;
        }

    for (int ks = 0; ks < KS; ++ks) {
        __syncthreads();   // previous step's fragment reads done
        // ---- A tile: 512 tasks t=(kb*128+row), LDS slot t (16B each) ----
#pragma unroll
        for (int it = 0; it < 2; ++it) {
            int t0 = it * 256 + w * 64;
            int t = t0 + lane;
            int row = t & 127, kb = t >> 7;
            size_t go = (size_t)(m0 + row) * K + ks * 32 + kb * 8;
            gload16(Ah_g + go, Ah + (size_t)t0 * 8);
            if constexpr (NT == 3) gload16(Al_g + go, Al + (size_t)t0 * 8);
        }
        // ---- B tile: linear copy of pre-transformed block ----
        {
            size_t bo = ((size_t)nb * KS + ks) * (BN * 32);
            constexpr int BT = 4 * BN;
            if constexpr (BT >= 256) {
#pragma unroll
                for (int it = 0; it < BT / 256; ++it) {
                    int t0 = it * 256 + w * 64;
                    size_t go = bo + (size_t)(t0 + lane) * 8;
                    gload16(Wh + go, Bh + (size_t)t0 * 8);
                    if constexpr (NT == 3) gload16(Wl + go, Bl + (size_t)t0 * 8);
                }
            } else {
                if (tid < BT) {
                    int t0 = w * 64;
                    size_t go = bo + (size_t)(t0 + lane) * 8;
                    gload16(Wh + go, Bh + (size_t)t0 * 8);
                    if constexpr (NT == 3) gload16(Wl + go, Bl + (size_t)t0 * 8);
                }
            }
        }
        __syncthreads();   // drains vmcnt (compiler) + all waves staged

        // ---- fragments + MFMA ----
        short8 ah[WM], bh[WN];
        short8 al[WM], bl[WN];
#pragma unroll
        for (int m = 0; m < WM; ++m) {
            int ro = (g << 7) + wrow0 + m * 16 + lr;
            ah[m] = *(const short8*)&Ah[ro * 8];
            if constexpr (NT == 3) al[m] = *(const short8*)&Al[ro * 8];
        }
#pragma unroll
        for (int n = 0; n < WN; ++n) {
            int co = g * BN + wcol0 + n * 16 + lr;
            bh[n] = *(const short8*)&Bh[co * 8];
            if constexpr (NT == 3) bl[n] = *(const short8*)&Bl[co * 8];
        }
#pragma unroll
        for (int m = 0; m < WM; ++m)
#pragma unroll
            for (int n = 0; n < WN; ++n) {
                acc[m][n] = __builtin_amdgcn_mfma_f32_16x16x32_bf16(
                    ah[m], bh[n], acc[m][n], 0, 0, 0);
                if constexpr (NT == 3) {
                    acc[m][n] = __builtin_amdgcn_mfma_f32_16x16x32_bf16(
                        ah[m], bl[n], acc[m][n], 0, 0, 0);
                    acc[m][n] = __builtin_amdgcn_mfma_f32_16x16x32_bf16(
                        al[m], bh[n], acc[m][n], 0, 0, 0);
                }
            }
    }

    // ---- epilogue: bias + act, LDS transpose, coalesced stores ----
    float bv[WN];
#pragma unroll
    for (int n = 0; n < WN; ++n) bv[n] = bias[n0 + wcol0 + n * 16 + lr];

    unsigned short* Sb = smem;
    float* Sf = (float*)smem;
    constexpr int NPASS = (OUT == 0) ? 2 : 1;

#pragma unroll
    for (int p = 0; p < NPASS; ++p) {
        __syncthreads();
#pragma unroll
        for (int m = 0; m < WM; ++m)
#pragma unroll
            for (int n = 0; n < WN; ++n)
#pragma unroll
                for (int q = 0; q < 4; ++q) {
                    int rl = wrow0 + m * 16 + g * 4 + q;
                    int cl = wcol0 + n * 16 + lr;
                    float x = acc[m][n][q] + bv[n];
                    if (ACT == 0) x = fmaxf(x, 0.f);
                    else x = tanhf(x);
                    if constexpr (OUT == 2) {
                        Sf[rl * BN + cl] = x;
                    } else {
                        unsigned short hb_ = f2bf(x);
                        Sb[rl * BN + cl] = (p == 0) ? hb_ : f2bf(x - bf2f(hb_));
                    }
                }
        __syncthreads();
        if constexpr (OUT == 2) {
            constexpr int SL = BN / 4;
#pragma unroll
            for (int it = 0; it < (128 * SL) / 256; ++it) {
                int idx = tid + it * 256;
                int row = idx / SL, sl = idx % SL;
                *(f32x4*)((float*)out0 + (size_t)(m0 + row) * NTOT + n0 + sl * 4)
                    = *(const f32x4*)&Sf[row * BN + sl * 4];
            }
        } else {
            constexpr int SL = BN / 8;
            unsigned short* dst = (unsigned short*)((p == 0) ? out0 : out1);
#pragma unroll
            for (int it = 0; it < (128 * SL) / 256; ++it) {
                int idx = tid + it * 256;
                int row = idx / SL, sl = idx % SL;
                *(short8*)&dst[(size_t)(m0 + row) * NTOT + n0 + sl * 8]
                    = *(const short8*)&Sb[row * BN + sl * 8];
            }
        }
    }
}

// ---------------------------------------------------------------------------
// Build encoder input planes: sa = [state | action] as bf16 hi + lo.
// ---------------------------------------------------------------------------
__global__ void sa_pre(const float* __restrict__ state, const float* __restrict__ action,
                       unsigned short* __restrict__ saH, unsigned short* __restrict__ saL)
{
    int idx = blockIdx.x * 256 + threadIdx.x;
    int row = idx / 12, q = idx % 12;
    const float* src = (q < 8) ? (state + (size_t)row * 64 + q * 8)
                               : (action + (size_t)row * 32 + (q - 8) * 8);
    f32x4 v0 = *(const f32x4*)src;
    f32x4 v1 = *(const f32x4*)(src + 4);
    short8 h, l;
#pragma unroll
    for (int j = 0; j < 8; ++j) {
        float x = (j < 4) ? v0[j] : v1[j - 4];
        unsigned short hb_ = f2bf(x);
        h[j] = (short)hb_;
        l[j] = (short)f2bf(x - bf2f(hb_));
    }
    *(short8*)&saH[(size_t)row * 96 + q * 8] = h;
    *(short8*)&saL[(size_t)row * 96 + q * 8] = l;
}

// xz plane cols 0..63 = bf16(state)
__global__ void xz_pre(const float* __restrict__ state, unsigned short* __restrict__ xz)
{
    int idx = blockIdx.x * 256 + threadIdx.x;
    int row = idx >> 4, q = idx & 15;
    f32x4 v = *(const f32x4*)&state[(size_t)row * 64 + q * 4];
    unsigned short o[4];
    o[0] = f2bf(v[0]); o[1] = f2bf(v[1]); o[2] = f2bf(v[2]); o[3] = f2bf(v[3]);
    *(uint2*)&xz[(size_t)row * 128 + q * 4] = *(uint2*)o;
}

// ---------------------------------------------------------------------------
// Fused VQ + latent head. Tracks top-2 distances; rows with gap < TAU get
// appended to `list` for exact fp32 recompute (fix_rows). mean/std/z depend
// only on the gathered codebook row -> fp32-exact given a correct argmin.
// ---------------------------------------------------------------------------
__global__ __launch_bounds__(256) void vq_latent(
    const float* __restrict__ midz,
    const float* __restrict__ codebook,
    const float* __restrict__ cbn,
    const float* __restrict__ mean_w, const float* __restrict__ mean_b,
    const float* __restrict__ logstd_w, const float* __restrict__ logstd_b,
    const float* __restrict__ eps,
    float* __restrict__ mean_out,
    float* __restrict__ std_out,
    unsigned short* __restrict__ xz,
    int* __restrict__ ctr, int* __restrict__ list)
{
    __shared__ float smem[13120];
    float* Zt = smem;                    // [64][132]
    float* Ct = smem + 8448;             // [64][68]
    float* cn = smem + 12800;            // [64]
    float* zn = smem + 12864;            // [128]
    int* sidx = (int*)(smem + 12992);    // [128]

    const int tid = threadIdx.x;
    const int m0 = blockIdx.x * 128;
    const int r = tid >> 4;
    const int c = tid & 15;

#pragma unroll
    for (int it = 0; it < 8; ++it) {
        int idx = tid + it * 256;
        int row = idx >> 4;
        int f = idx & 15;
        float4 v = *(const float4*)(midz + (size_t)(m0 + row) * 64 + f * 4);
        Zt[(f * 4 + 0) * 132 + row] = v.x;
        Zt[(f * 4 + 1) * 132 + row] = v.y;
        Zt[(f * 4 + 2) * 132 + row] = v.z;
        Zt[(f * 4 + 3) * 132 + row] = v.w;
    }
    __syncthreads();
    if (tid < 128) {
        float s = 0.f;
#pragma unroll
        for (int k = 0; k < 64; ++k) {
            float v = Zt[k * 132 + tid];
            s = fmaf(v, v, s);
        }
        zn[tid] = s;
    }

    float best[8], sec[8];
    int bidx[8];
#pragma unroll
    for (int i = 0; i < 8; ++i) { best[i] = 3.4e38f; sec[i] = 3.4e38f; bidx[i] = 0x7fffffff; }

    for (int ch = 0; ch < 16; ++ch) {
        int e0 = ch * 64;
        __syncthreads();
#pragma unroll
        for (int it = 0; it < 4; ++it) {
            int idx = tid + it * 256;
            int e = idx >> 4;
            int f = idx & 15;
            float4 v = *(const float4*)(codebook + (size_t)(e0 + e) * 64 + f * 4);
            Ct[(f * 4 + 0) * 68 + e] = v.x;
            Ct[(f * 4 + 1) * 68 + e] = v.y;
            Ct[(f * 4 + 2) * 68 + e] = v.z;
            Ct[(f * 4 + 3) * 68 + e] = v.w;
        }
        if (tid < 64) cn[tid] = cbn[e0 + tid];
        __syncthreads();

        float acc[8][4];
#pragma unroll
        for (int i = 0; i < 8; ++i)
#pragma unroll
            for (int j = 0; j < 4; ++j) acc[i][j] = 0.f;

#pragma unroll 8
        for (int kk = 0; kk < 64; ++kk) {
            float a[8], b[4];
            float4 av0 = *(const float4*)&Zt[kk * 132 + r * 8];
            float4 av1 = *(const float4*)&Zt[kk * 132 + r * 8 + 4];
            a[0] = av0.x; a[1] = av0.y; a[2] = av0.z; a[3] = av0.w;
            a[4] = av1.x; a[5] = av1.y; a[6] = av1.z; a[7] = av1.w;
            float4 bv = *(const float4*)&Ct[kk * 68 + c * 4];
            b[0] = bv.x; b[1] = bv.y; b[2] = bv.z; b[3] = bv.w;
#pragma unroll
            for (int i = 0; i < 8; ++i)
#pragma unroll
                for (int j = 0; j < 4; ++j)
                    acc[i][j] = fmaf(a[i], b[j], acc[i][j]);
        }
#pragma unroll
        for (int i = 0; i < 8; ++i) {
            float zni = zn[r * 8 + i];
#pragma unroll
            for (int j = 0; j < 4; ++j) {
                int e = c * 4 + j;
                float s = (zni + cn[e]) - 2.0f * acc[i][j];
                int gi = e0 + e;
                if (s < best[i] || (s == best[i] && gi < bidx[i])) {
                    sec[i] = best[i];
                    best[i] = s;
                    bidx[i] = gi;
                } else {
                    sec[i] = fminf(sec[i], s);
                }
            }
        }
    }

    // top-2 merge across 16 col-lanes
#pragma unroll
    for (int i = 0; i < 8; ++i) {
#pragma unroll
        for (int m = 1; m < 16; m <<= 1) {
            float ob = __shfl_xor(best[i], m, 64);
            int oi = __shfl_xor(bidx[i], m, 64);
            float os = __shfl_xor(sec[i], m, 64);
            if (ob < best[i] || (ob == best[i] && oi < bidx[i])) {
                sec[i] = fminf(best[i], os);
                best[i] = ob;
                bidx[i] = oi;
            } else {
                sec[i] = fminf(sec[i], ob);
            }
        }
    }
    __syncthreads();
    if (c == 0) {
#pragma unroll
        for (int i = 0; i < 8; ++i) {
            sidx[r * 8 + i] = bidx[i];
            if (sec[i] - best[i] < TAU) {
                int p = atomicAdd(ctr, 1);
                list[p] = m0 + r * 8 + i;
            }
        }
    }

    float* mw = smem;
    float* lw = smem + 4160;
#pragma unroll
    for (int it = 0; it < 4; ++it) {
        int idx = tid + it * 256;
        int k = idx >> 4;
        int f = idx & 15;
        float4 v = *(const float4*)(mean_w + (size_t)k * 64 + f * 4);
        mw[k * 65 + f * 4 + 0] = v.x;
        mw[k * 65 + f * 4 + 1] = v.y;
        mw[k * 65 + f * 4 + 2] = v.z;
        mw[k * 65 + f * 4 + 3] = v.w;
        float4 w2 = *(const float4*)(logstd_w + (size_t)k * 64 + f * 4);
        lw[k * 65 + f * 4 + 0] = w2.x;
        lw[k * 65 + f * 4 + 1] = w2.y;
        lw[k * 65 + f * 4 + 2] = w2.z;
        lw[k * 65 + f * 4 + 3] = w2.w;
    }
    __syncthreads();

    {
        int row = tid >> 1;
        int d0 = (tid & 1) * 32;
        int e = sidx[row];
        const float* cb = codebook + (size_t)e * 64;
        float mv[32], lv[32];
#pragma unroll
        for (int d = 0; d < 32; ++d) {
            mv[d] = mean_b[d0 + d];
            lv[d] = logstd_b[d0 + d];
        }
        for (int k = 0; k < 64; ++k) {
            float zk = cb[k];
#pragma unroll
            for (int d = 0; d < 32; ++d) {
                mv[d] = fmaf(zk, mw[k * 65 + d0 + d], mv[d]);
                lv[d] = fmaf(zk, lw[k * 65 + d0 + d], lv[d]);
            }
        }
        size_t ro = (size_t)(m0 + row) * 64 + d0;
        size_t xo = (size_t)(m0 + row) * 128 + 64 + d0;
#pragma unroll
        for (int d = 0; d < 32; ++d) {
            float mean = mv[d];
            float ls = fminf(fmaxf(lv[d], -4.f), 15.f);
            float sd = expf(ls);
            float z = fmaf(sd, eps[ro + d], mean);
            mean_out[ro + d] = mean;
            std_out[ro + d] = sd;
            xz[xo + d] = f2bf(z);
        }
    }
}

// ---------------------------------------------------------------------------
// Exact fp32 recompute of flagged rows (batch 8 rows/block to amortize the
// enc_w2 stream). Reproduces the reference encoder + argmin in fp32, then
// overwrites mean/std/xz for those rows.
// ---------------------------------------------------------------------------
#define FROWS 8
__global__ __launch_bounds__(256) void fix_rows(
    const int* __restrict__ ctr, const int* __restrict__ list, int r0,
    const float* __restrict__ state, const float* __restrict__ action,
    const float* __restrict__ eps,
    const float* __restrict__ ew1, const float* __restrict__ eb1,
    const float* __restrict__ ew2, const float* __restrict__ eb2,
    const float* __restrict__ ew3, const float* __restrict__ eb3,
    const float* __restrict__ mean_w, const float* __restrict__ mean_b,
    const float* __restrict__ logstd_w, const float* __restrict__ logstd_b,
    const float* __restrict__ codebook, const float* __restrict__ cbn,
    float* __restrict__ mean_out, float* __restrict__ std_out,
    unsigned short* __restrict__ xz)
{
    __shared__ float in_s[FROWS][96];
    __shared__ float buf[FROWS][1024];      // 32 KB, multi-purpose
    __shared__ float mzs[FROWS][64];
    __shared__ float zns[FROWS];
    __shared__ int rows_s[FROWS];
    __shared__ int am_s[FROWS];

    const int tid = threadIdx.x;
    const int cnt = *ctr;

    for (int base = blockIdx.x * FROWS; base < cnt; base += gridDim.x * FROWS) {
        int nr = min(FROWS, cnt - base);
        __syncthreads();
        if (tid < FROWS) rows_s[tid] = list[base + ((tid < nr) ? tid : 0)];
        __syncthreads();
        // stage inputs
        for (int t = tid; t < FROWS * 96; t += 256) {
            int rr = t / 96, k = t % 96;
            size_t grow = (size_t)(r0 + rows_s[rr]);
            in_s[rr][k] = (k < 64) ? state[grow * 64 + k]
                                   : action[grow * 32 + (k - 64)];
        }
        __syncthreads();
        // ---- L1: h1 = relu(in @ ew1 + b1) ----
        float a1[FROWS][4];
#pragma unroll
        for (int rr = 0; rr < FROWS; ++rr)
#pragma unroll
            for (int j = 0; j < 4; ++j) a1[rr][j] = 0.f;
        for (int k = 0; k < 96; ++k) {
            float w0 = ew1[(size_t)k * 1024 + tid];
            float w1 = ew1[(size_t)k * 1024 + tid + 256];
            float w2 = ew1[(size_t)k * 1024 + tid + 512];
            float w3 = ew1[(size_t)k * 1024 + tid + 768];
#pragma unroll
            for (int rr = 0; rr < FROWS; ++rr) {
                float av = in_s[rr][k];
                a1[rr][0] = fmaf(av, w0, a1[rr][0]);
                a1[rr][1] = fmaf(av, w1, a1[rr][1]);
                a1[rr][2] = fmaf(av, w2, a1[rr][2]);
                a1[rr][3] = fmaf(av, w3, a1[rr][3]);
            }
        }
#pragma unroll
        for (int rr = 0; rr < FROWS; ++rr)
#pragma unroll
            for (int j = 0; j < 4; ++j)
                buf[rr][tid + j * 256] = fmaxf(a1[rr][j] + eb1[tid + j * 256], 0.f);
        __syncthreads();
        // ---- L2: h2 = relu(h1 @ ew2 + b2) ----
        float a2[FROWS][4];
#pragma unroll
        for (int rr = 0; rr < FROWS; ++rr)
#pragma unroll
            for (int j = 0; j < 4; ++j) a2[rr][j] = 0.f;
        for (int k = 0; k < 1024; ++k) {
            float w0 = ew2[(size_t)k * 1024 + tid];
            float w1 = ew2[(size_t)k * 1024 + tid + 256];
            float w2 = ew2[(size_t)k * 1024 + tid + 512];
            float w3 = ew2[(size_t)k * 1024 + tid + 768];
#pragma unroll
            for (int rr = 0; rr < FROWS; ++rr) {
                float av = buf[rr][k];
                a2[rr][0] = fmaf(av, w0, a2[rr][0]);
                a2[rr][1] = fmaf(av, w1, a2[rr][1]);
                a2[rr][2] = fmaf(av, w2, a2[rr][2]);
                a2[rr][3] = fmaf(av, w3, a2[rr][3]);
            }
        }
        __syncthreads();   // all reads of h1 done before overwrite
#pragma unroll
        for (int rr = 0; rr < FROWS; ++rr)
#pragma unroll
            for (int j = 0; j < 4; ++j)
                buf[rr][tid + j * 256] = fmaxf(a2[rr][j] + eb2[tid + j * 256], 0.f);
        __syncthreads();
        // ---- L3: mid_z = relu(h2 @ ew3 + b3) ----
#pragma unroll
        for (int jo = 0; jo < 2; ++jo) {
            int o = tid + jo * 256;      // 512 outs
            int rr = o >> 6, d = o & 63;
            float s = eb3[d];
            for (int k = 0; k < 1024; ++k)
                s = fmaf(buf[rr][k], ew3[(size_t)k * 64 + d], s);
            mzs[rr][d] = fmaxf(s, 0.f);
        }
        __syncthreads();
        if (tid < FROWS) {
            float s = 0.f;
#pragma unroll
            for (int k = 0; k < 64; ++k) s = fmaf(mzs[tid][k], mzs[tid][k], s);
            zns[tid] = s;
        }
        __syncthreads();
        // ---- scores + per-thread argmin over 4 codes ----
        float bb[FROWS];
        int bi[FROWS];
#pragma unroll
        for (int rr = 0; rr < FROWS; ++rr) { bb[rr] = 3.4e38f; bi[rr] = 0x7fffffff; }
#pragma unroll
        for (int j = 0; j < 4; ++j) {
            int code = tid + j * 256;
            float dot[FROWS];
#pragma unroll
            for (int rr = 0; rr < FROWS; ++rr) dot[rr] = 0.f;
            for (int k = 0; k < 64; ++k) {
                float cv = codebook[(size_t)code * 64 + k];
#pragma unroll
                for (int rr = 0; rr < FROWS; ++rr)
                    dot[rr] = fmaf(mzs[rr][k], cv, dot[rr]);
            }
            float cnv = cbn[code];
#pragma unroll
            for (int rr = 0; rr < FROWS; ++rr) {
                float s = (zns[rr] + cnv) - 2.0f * dot[rr];
                if (s < bb[rr] || (s == bb[rr] && code < bi[rr])) {
                    bb[rr] = s; bi[rr] = code;
                }
            }
        }
        // reduce across 256 threads (buf reused as scratch)
        float* sv = &buf[0][0];              // 2048 floats
        int* si = (int*)(&buf[0][0] + 2048); // 2048 ints
#pragma unroll
        for (int rr = 0; rr < FROWS; ++rr) {
            sv[rr * 256 + tid] = bb[rr];
            si[rr * 256 + tid] = bi[rr];
        }
        __syncthreads();
        if (tid < FROWS) {
            float b = 3.4e38f;
            int ix = 0x7fffffff;
            for (int t = 0; t < 256; ++t) {
                float v = sv[tid * 256 + t];
                int iv = si[tid * 256 + t];
                if (v < b || (v == b && iv < ix)) { b = v; ix = iv; }
            }
            am_s[tid] = ix;
        }
        __syncthreads();
        // ---- outputs for the nr rows ----
#pragma unroll
        for (int jo = 0; jo < 2; ++jo) {
            int o = tid + jo * 256;
            int rr = o >> 6, d = o & 63;
            if (rr < nr) {
                int e = am_s[rr];
                size_t grow = (size_t)(r0 + rows_s[rr]);
                float mv = mean_b[d], lv = logstd_b[d];
                const float* cb = codebook + (size_t)e * 64;
                for (int k = 0; k < 64; ++k) {
                    float zk = cb[k];
                    mv = fmaf(zk, mean_w[(size_t)k * 64 + d], mv);
                    lv = fmaf(zk, logstd_w[(size_t)k * 64 + d], lv);
                }
                float ls = fminf(fmaxf(lv, -4.f), 15.f);
                float sd = expf(ls);
                float z = fmaf(sd, eps[grow * 64 + d], mv);
                mean_out[grow * 64 + d] = mv;
                std_out[grow * 64 + d] = sd;
                xz[(size_t)rows_s[rr] * 128 + 64 + d] = f2bf(z);
            }
        }
        __syncthreads();
    }
}

// ---------------------------------------------------------------------------
extern "C" void kernel_launch(void* const* d_in, const int* in_sizes, int n_in,
                              void* d_out, int out_size, void* d_ws, size_t ws_size,
                              hipStream_t stream)
{
    const float* state    = (const float*)d_in[0];
    const float* action   = (const float*)d_in[1];
    const float* eps      = (const float*)d_in[2];
    const float* enc_w1   = (const float*)d_in[3];
    const float* enc_b1   = (const float*)d_in[4];
    const float* enc_w2   = (const float*)d_in[5];
    const float* enc_b2   = (const float*)d_in[6];
    const float* enc_w3   = (const float*)d_in[7];
    const float* enc_b3   = (const float*)d_in[8];
    const float* mean_w   = (const float*)d_in[9];
    const float* mean_b   = (const float*)d_in[10];
    const float* logstd_w = (const float*)d_in[11];
    const float* logstd_b = (const float*)d_in[12];
    const float* codebook = (const float*)d_in[13];
    const float* dec_w1   = (const float*)d_in[14];
    const float* dec_b1   = (const float*)d_in[15];
    const float* dec_w2   = (const float*)d_in[16];
    const float* dec_b2   = (const float*)d_in[17];
    const float* dec_w3   = (const float*)d_in[18];
    const float* dec_b3   = (const float*)d_in[19];

    float* out = (float*)d_out;
    float* u_out = out;
    float* mean_out = out + (size_t)B_TOTAL * 32;
    float* std_out = mean_out + (size_t)B_TOTAL * 64;

    // ---- fixed ws region ----
    char* base = (char*)d_ws;
    float* cbn = (float*)base;                                   // 4096
    unsigned short* W1h = (unsigned short*)(base + 4096);        // 196608
    unsigned short* W1l = (unsigned short*)(base + 200704);      // 196608
    unsigned short* W2h = (unsigned short*)(base + 397312);      // 2097152
    unsigned short* W2l = (unsigned short*)(base + 2494464);     // 2097152
    unsigned short* W3h = (unsigned short*)(base + 4591616);     // 131072
    unsigned short* W3l = (unsigned short*)(base + 4722688);     // 131072
    unsigned short* W4h = (unsigned short*)(base + 4853760);     // 262144
    unsigned short* W5h = (unsigned short*)(base + 5115904);     // 2097152
    unsigned short* W6h = (unsigned short*)(base + 7213056);     // 65536
    int* ctr            = (int*)(base + 7278592);                // 256
    int* flag_list      = (int*)(base + 7278848);                // 262144
    const size_t FIXED  = 7540992;

    // per-row: saH 192 + saL 192 + h1H 2048 + h1L 2048 + h2H 2048 + h2L 2048
    //          + mz 256 + xz 256 = 11088 B
    const size_t per_row = 11088;
    long maxC = (ws_size > FIXED) ? (long)((ws_size - FIXED) / per_row) : 0;
    int C = (int)(maxC / 128) * 128;
    if (C > B_TOTAL) C = B_TOTAL;
    if (C < 128) C = 128;

    char* dyn = base + FIXED;
    unsigned short* saH = (unsigned short*)dyn;                   // [C,96]
    unsigned short* saL = saH + (size_t)C * 96;
    unsigned short* h1H = saL + (size_t)C * 96;                   // [C,1024]
    unsigned short* h1L = h1H + (size_t)C * 1024;
    unsigned short* h2H = h1L + (size_t)C * 1024;
    unsigned short* h2L = h2H + (size_t)C * 1024;
    float* mz = (float*)(h2L + (size_t)C * 1024);                 // [C,64]
    unsigned short* xz = (unsigned short*)(mz + (size_t)C * 64);  // [C,128]
    unsigned short* hc = h1H;   // decoder reuse
    unsigned short* hd = h2H;

    // ---- once per call ----
    cb_norms<<<dim3(4), dim3(256), 0, stream>>>(codebook, cbn);
    w_xform<3, 128><<<dim3(3, 8), dim3(256), 0, stream>>>(enc_w1, 96, 1024, W1h, W1l);
    w_xform<3, 128><<<dim3(32, 8), dim3(256), 0, stream>>>(enc_w2, 1024, 1024, W2h, W2l);
    w_xform<3, 64><<<dim3(32, 1), dim3(256), 0, stream>>>(enc_w3, 1024, 64, W3h, W3l);
    w_xform<1, 128><<<dim3(4, 8), dim3(256), 0, stream>>>(dec_w1, 128, 1024, W4h, nullptr);
    w_xform<1, 128><<<dim3(32, 8), dim3(256), 0, stream>>>(dec_w2, 1024, 1024, W5h, nullptr);
    w_xform<1, 32><<<dim3(32, 1), dim3(256), 0, stream>>>(dec_w3, 1024, 32, W6h, nullptr);

    for (int r0 = 0; r0 < B_TOTAL; r0 += C) {
        int M = (r0 + C <= B_TOTAL) ? C : (B_TOTAL - r0);
        int mt = M / 128;

        sa_pre<<<dim3(M * 12 / 256), dim3(256), 0, stream>>>(
            state + (size_t)r0 * SDIM, action + (size_t)r0 * ADIM, saH, saL);

        // encoder: 3-term split bf16 MFMA
        mfma_gemm<3, 128, 0, 0><<<dim3(mt, 8), dim3(256), 0, stream>>>(
            saH, saL, 96, W1h, W1l, enc_b1, h1H, h1L, 1024);
        mfma_gemm<3, 128, 0, 0><<<dim3(mt, 8), dim3(256), 0, stream>>>(
            h1H, h1L, 1024, W2h, W2l, enc_b2, h2H, h2L, 1024);
        mfma_gemm<3, 64, 2, 0><<<dim3(mt, 1), dim3(256), 0, stream>>>(
            h2H, h2L, 1024, W3h, W3l, enc_b3, mz, nullptr, 64);

        xz_pre<<<dim3(M / 16), dim3(256), 0, stream>>>(state + (size_t)r0 * SDIM, xz);

        zero_ctr<<<dim3(1), dim3(64), 0, stream>>>(ctr);
        vq_latent<<<dim3(mt), dim3(256), 0, stream>>>(
            mz, codebook, cbn, mean_w, mean_b, logstd_w, logstd_b,
            eps + (size_t)r0 * LDIM,
            mean_out + (size_t)r0 * LDIM, std_out + (size_t)r0 * LDIM, xz,
            ctr, flag_list);
        fix_rows<<<dim3(512), dim3(256), 0, stream>>>(
            ctr, flag_list, r0, state, action, eps,
            enc_w1, enc_b1, enc_w2, enc_b2, enc_w3, enc_b3,
            mean_w, mean_b, logstd_w, logstd_b, codebook, cbn,
            mean_out, std_out, xz);

        // decoder: plain bf16 MFMA
        mfma_gemm<1, 128, 1, 0><<<dim3(mt, 8), dim3(256), 0, stream>>>(
            xz, nullptr, 128, W4h, nullptr, dec_b1, hc, nullptr, 1024);
        mfma_gemm<1, 128, 1, 0><<<dim3(mt, 8), dim3(256), 0, stream>>>(
            hc, nullptr, 1024, W5h, nullptr, dec_b2, hd, nullptr, 1024);
        mfma_gemm<1, 32, 2, 1><<<dim3(mt, 1), dim3(256), 0, stream>>>(
            hd, nullptr, 1024, W6h, nullptr, dec_b3,
            u_out + (size_t)r0 * ADIM, nullptr, 32);
    }
}